// Round 3
// baseline (430.742 us; speedup 1.0000x reference)
//
#include <hip/hip_runtime.h>
#include <hip/hip_bf16.h>
#include <cstdint>
#include <cstddef>

#define N_NODES 50000
#define FDIM 512
#define NBKT 391        // ceil(50000/128) buckets of 128 dst nodes
#define CHUNK 8192      // edges per binning block
#define BCAP 4096       // max edges per bucket (Poisson(2046), sigma 45 -> cap is 45 sigma)

typedef __bf16 bf16_t;
typedef bf16_t bf16x8 __attribute__((ext_vector_type(8)));
typedef float f32x4 __attribute__((ext_vector_type(4)));

__device__ __forceinline__ unsigned short f2bf(float f) {
  union { float f; uint32_t u; } c; c.f = f;
  uint32_t u = c.u;
  uint32_t r = (u + 0x7fffu + ((u >> 16) & 1u)) >> 16;  // RNE
  return (unsigned short)r;
}
__device__ __forceinline__ float bf2f(unsigned short u) {
  union { uint32_t i; float f; } c; c.i = (uint32_t)u << 16; return c.f;
}
__device__ __forceinline__ float4 ld_bf4(const unsigned short* p) {
  ushort4 u = *(const ushort4*)p;
  float4 r; r.x = bf2f(u.x); r.y = bf2f(u.y); r.z = bf2f(u.z); r.w = bf2f(u.w);
  return r;
}
__device__ __forceinline__ void async16(const void* g, void* l) {
  __builtin_amdgcn_global_load_lds((const __attribute__((address_space(1))) void*)g,
                                   (__attribute__((address_space(3))) void*)l, 16, 0, 0);
}

// ---------------- CSR build: LDS-binned bucket sort, no global atomics ----------------
__global__ __launch_bounds__(256) void binA(const int* __restrict__ d1, const int* __restrict__ d2,
                                            int* __restrict__ M1, int* __restrict__ M2,
                                            int E1, int E2, int nch1, int nch2) {
  const int g = blockIdx.y;
  const int* dst = g ? d2 : d1;
  int* M = g ? M2 : M1;
  const int E = g ? E2 : E1;
  const int nch = g ? nch2 : nch1;
  const int chunk = blockIdx.x;
  if (chunk >= nch) return;
  __shared__ int cnt[NBKT];
  for (int j = threadIdx.x; j < NBKT; j += 256) cnt[j] = 0;
  __syncthreads();
  const int base = chunk * CHUNK;
#pragma unroll 4
  for (int i = 0; i < CHUNK / 256; i++) {
    int e = base + i * 256 + threadIdx.x;
    if (e < E) atomicAdd(&cnt[dst[e] >> 7], 1);
  }
  __syncthreads();
  for (int j = threadIdx.x; j < NBKT; j += 256) M[chunk * NBKT + j] = cnt[j];
}

__global__ __launch_bounds__(512) void bin_offsets(int* __restrict__ M1, int* __restrict__ M2,
                                                   int* __restrict__ bases,
                                                   int nch1, int nch2, int E1, int E2) {
  const int g = blockIdx.x;
  int* M = g ? M2 : M1;
  const int nch = g ? nch2 : nch1;
  int* base = bases + g * (NBKT + 1);
  const int E = g ? E2 : E1;
  const int t = threadIdx.x;
  __shared__ int tot[512];
  int running = 0;
  if (t < NBKT) {
#pragma unroll 4
    for (int b = 0; b < nch; b++) {
      int v = M[b * NBKT + t];
      M[b * NBKT + t] = running;
      running += v;
    }
  }
  tot[t] = (t < NBKT) ? running : 0;
  __syncthreads();
  for (int off = 1; off < 512; off <<= 1) {
    int u = (t >= off) ? tot[t - off] : 0;
    __syncthreads();
    tot[t] += u;
    __syncthreads();
  }
  int ex = (t == 0) ? 0 : tot[t - 1];
  if (t < NBKT) {
    base[t] = ex;
#pragma unroll 4
    for (int b = 0; b < nch; b++) M[b * NBKT + t] += ex;
  }
  if (t == NBKT) base[NBKT] = E;
}

__global__ __launch_bounds__(256) void binB(const int* __restrict__ s1, const int* __restrict__ d1,
                                            const int* __restrict__ M1, unsigned* __restrict__ eb1,
                                            int E1, int nch1,
                                            const int* __restrict__ s2, const int* __restrict__ d2,
                                            const int* __restrict__ M2, unsigned* __restrict__ eb2,
                                            int E2, int nch2) {
  const int g = blockIdx.y;
  const int* src = g ? s2 : s1;
  const int* dst = g ? d2 : d1;
  const int* M = g ? M2 : M1;
  unsigned* eb = g ? eb2 : eb1;
  const int E = g ? E2 : E1;
  const int nch = g ? nch2 : nch1;
  const int chunk = blockIdx.x;
  if (chunk >= nch) return;
  __shared__ int gbase[NBKT];
  __shared__ int cur[NBKT];
  for (int j = threadIdx.x; j < NBKT; j += 256) {
    gbase[j] = M[chunk * NBKT + j];
    cur[j] = 0;
  }
  __syncthreads();
  const int base = chunk * CHUNK;
#pragma unroll 4
  for (int i = 0; i < CHUNK / 256; i++) {
    int e = base + i * 256 + threadIdx.x;
    if (e < E) {
      int d = dst[e];
      int b = d >> 7;
      int pos = gbase[b] + atomicAdd(&cur[b], 1);
      eb[pos] = ((unsigned)d << 16) | (unsigned)src[e];
    }
  }
}

__global__ __launch_bounds__(256) void binC(const unsigned* __restrict__ eb1,
                                            const unsigned* __restrict__ eb2,
                                            const int* __restrict__ bases,
                                            int* __restrict__ rp1, float* __restrict__ dv1,
                                            int* __restrict__ cs1,
                                            int* __restrict__ rp2, float* __restrict__ dv2,
                                            int* __restrict__ cs2, int n) {
  const int g = blockIdx.y;
  const unsigned* eb = g ? eb2 : eb1;
  const int* base = bases + g * (NBKT + 1);
  int* rp = g ? rp2 : rp1;
  float* dv = g ? dv2 : dv1;
  int* cs = g ? cs2 : cs1;
  const int bkt = blockIdx.x;
  const int e0 = base[bkt], e1 = base[bkt + 1];
  const int cnt = e1 - e0;
  const int node0 = bkt << 7;
  const int t = threadIdx.x;
  __shared__ unsigned stage[BCAP];
  __shared__ int sorted[BCAP];
  __shared__ int dcnt[128], dcur[128], dscan[128];
  if (t < 128) dcnt[t] = 0;
  __syncthreads();
  for (int i = t; i < cnt; i += 256) {
    unsigned pe = eb[e0 + i];
    stage[i] = pe;
    atomicAdd(&dcnt[(pe >> 16) & 127], 1);
  }
  __syncthreads();
  if (t < 128) dscan[t] = dcnt[t];
  __syncthreads();
  for (int off = 1; off < 128; off <<= 1) {
    int u = (t < 128 && t >= off) ? dscan[t - off] : 0;
    __syncthreads();
    if (t < 128) dscan[t] += u;
    __syncthreads();
  }
  if (t < 128) {
    int ex = dscan[t] - dcnt[t];
    dcur[t] = ex;
    int node = node0 + t;
    if (node < n) {
      rp[node] = e0 + ex;
      dv[node] = rsqrtf((float)dcnt[t] + 1.0f);
    }
  }
  __syncthreads();
  for (int i = t; i < cnt; i += 256) {
    unsigned pe = stage[i];
    int d = (pe >> 16) & 127;
    int pos = atomicAdd(&dcur[d], 1);
    sorted[pos] = (int)(pe & 0xFFFFu);
  }
  __syncthreads();
  for (int i = t; i < cnt; i += 256) cs[e0 + i] = sorted[i];
  if (bkt == NBKT - 1 && t == 0) rp[n] = base[NBKT];
}

// ---------------- weight converts ----------------
// WcatT[384][512]: n<256 -> W10 col n; 256<=n<320 -> W20 col n-256; else 0 (pad)
// W21T[256][64]: W21 transposed
__global__ void cvt_w(const float* __restrict__ W10, const float* __restrict__ W20,
                      const float* __restrict__ W21, unsigned short* __restrict__ WcatT,
                      unsigned short* __restrict__ W21T) {
  int j = blockIdx.x * 256 + threadIdx.x;
  const int T1 = 384 * 512;
  if (j < T1) {
    int n = j >> 9, k = j & 511;
    float v = (n < 256) ? W10[k * 256 + n] : ((n < 320) ? W20[k * 64 + (n - 256)] : 0.f);
    WcatT[j] = f2bf(v);
  } else {
    int j2 = j - T1;
    if (j2 < 256 * 64) {
      int n = j2 >> 6, k = j2 & 63;
      W21T[j2] = f2bf(W21[k * 256 + n]);
    }
  }
}

// ---------------- fused cvt + GEMM1: [Xh1b|Xh2b] = bf16(X) @ WcatT^T ----------------
// BM=128, BN=192, BK=64, grid (391, 2), 256 threads (4 waves 2Mx2N, wave = 64x96).
// LDS 40 KB (As 16K + Bs 24K) -> ~3 blocks/CU.  T14 async-split: next k-step's A (f32)
// prefetched into registers, kept in flight ACROSS the barrier via counted
// s_waitcnt vmcnt(8) (drains only the 6 B global_load_lds) -> A latency hides under MFMA.
// Order guarantee: prefetch sits in its own BB after the async16 block (program order =
// VMEM issue order), plus sched_barrier(0) pins the machine scheduler.
__global__ __launch_bounds__(256) void g1w(const float* __restrict__ X,
                                           const unsigned short* __restrict__ B,
                                           unsigned short* __restrict__ o1,
                                           unsigned short* __restrict__ o2, int M) {
  __shared__ __attribute__((aligned(16))) unsigned short As[128 * 64];  // 16 KB
  __shared__ __attribute__((aligned(16))) unsigned short Bs[192 * 64];  // 24 KB
  const int tid = threadIdx.x;
  const int w = tid >> 6, lane = tid & 63;
  const int row0 = blockIdx.x * 128;
  const int n0 = blockIdx.y * 192;
  const int wm = w >> 1, wn = w & 1;          // wave 2x2 grid, each 64(M) x 96(N)
  const int mlane = lane & 15, q = lane >> 4;

  // per-thread A-stage coordinates (16 threads per row, 16 float4 per row)
  const int ar = tid >> 4;        // base row (0..15), +16 per i
  const int ac4 = tid & 15;       // float4 column

  f32x4 acc[4][6];
#pragma unroll
  for (int mi = 0; mi < 4; mi++)
#pragma unroll
    for (int ni = 0; ni < 6; ni++) {
      f32x4 z = {0.f, 0.f, 0.f, 0.f};
      acc[mi][ni] = z;
    }

  float4 areg[8];
  // prologue: issue A-loads for k0=0
#pragma unroll
  for (int i = 0; i < 8; i++) {
    int gr = row0 + i * 16 + ar; if (gr > M - 1) gr = M - 1;
    areg[i] = *(const float4*)(X + (size_t)gr * 512 + ac4 * 4);
  }

  for (int k0 = 0; k0 < 512; k0 += 64) {
    __syncthreads();  // S1: prior frag reads of As/Bs done; areg (A[k]) arrived
    // cvt A[k] -> LDS (bf16)
#pragma unroll
    for (int i = 0; i < 8; i++) {
      ushort4 o;
      o.x = f2bf(areg[i].x); o.y = f2bf(areg[i].y);
      o.z = f2bf(areg[i].z); o.w = f2bf(areg[i].w);
      *(ushort4*)&As[(i * 16 + ar) * 64 + ac4 * 4] = o;
    }
    // stage B[k] via global_load_lds (6 per thread: 192 rows x 8 chunks of 16B)
#pragma unroll
    for (int i = 0; i < 6; i++) {
      int idx = i * 256 + tid;
      int rw = idx >> 3, c8 = idx & 7;
      async16(B + (size_t)(n0 + rw) * 512 + k0 + c8 * 8, &Bs[rw * 64 + c8 * 8]);
    }
    __builtin_amdgcn_sched_barrier(0);
    const bool lastk = (k0 == 448);
    if (!lastk) {
      // prefetch A[k+1] into regs (stays in flight across the barrier)
#pragma unroll
      for (int i = 0; i < 8; i++) {
        int gr = row0 + i * 16 + ar; if (gr > M - 1) gr = M - 1;
        areg[i] = *(const float4*)(X + (size_t)gr * 512 + (k0 + 64) + ac4 * 4);
      }
    }
    __builtin_amdgcn_sched_barrier(0);
    if (!lastk) {
      // drain the 6 oldest VMEM (B->LDS) + all ds_writes; leave 8 A-prefetch in flight
      asm volatile("s_waitcnt vmcnt(8) lgkmcnt(0)" ::: "memory");
    } else {
      asm volatile("s_waitcnt vmcnt(0) lgkmcnt(0)" ::: "memory");
    }
    __builtin_amdgcn_sched_barrier(0);
    __builtin_amdgcn_s_barrier();   // S2: As/Bs ready for all waves
    __builtin_amdgcn_sched_barrier(0);
#pragma unroll
    for (int kk = 0; kk < 2; kk++) {
      bf16x8 af[4], bfr[6];
#pragma unroll
      for (int mi = 0; mi < 4; mi++)
        af[mi] = *(const bf16x8*)&As[(wm * 64 + mi * 16 + mlane) * 64 + kk * 32 + q * 8];
#pragma unroll
      for (int ni = 0; ni < 6; ni++)
        bfr[ni] = *(const bf16x8*)&Bs[(wn * 96 + ni * 16 + mlane) * 64 + kk * 32 + q * 8];
#pragma unroll
      for (int mi = 0; mi < 4; mi++)
#pragma unroll
        for (int ni = 0; ni < 6; ni++)
          acc[mi][ni] = __builtin_amdgcn_mfma_f32_16x16x32_bf16(af[mi], bfr[ni], acc[mi][ni], 0, 0, 0);
    }
  }

#pragma unroll
  for (int mi = 0; mi < 4; mi++)
#pragma unroll
    for (int ni = 0; ni < 6; ni++) {
      int c = n0 + wn * 96 + ni * 16 + mlane;
#pragma unroll
      for (int rg = 0; rg < 4; rg++) {
        int r = row0 + wm * 64 + mi * 16 + q * 4 + rg;  // C/D: col=lane&15, row=(lane>>4)*4+reg
        if (r < M) {
          float v = acc[mi][ni][rg];
          if (c < 256) o1[(size_t)r * 256 + c] = f2bf(v);
          else if (c < 320) o2[(size_t)r * 64 + (c - 256)] = f2bf(v);
        }
      }
    }
}

// ---------------- propagation (gather-CSR, bf16 rows, fp32 accum) ----------------
__global__ __launch_bounds__(256) void prop256(const unsigned short* __restrict__ H,
                                               const int* __restrict__ rp,
                                               const int* __restrict__ cs,
                                               const float* __restrict__ dinv,
                                               const float* __restrict__ bias,
                                               float* __restrict__ out, int n) {
  const int i = blockIdx.x * 4 + (threadIdx.x >> 6);
  const int l = threadIdx.x & 63;
  if (i >= n) return;
  const float di = dinv[i];
  float4 self = ld_bf4(H + (size_t)i * 256 + l * 4);
  float4 acc;
  acc.x = di * self.x; acc.y = di * self.y; acc.z = di * self.z; acc.w = di * self.w;
  const int e1 = rp[i + 1];
#pragma unroll 4
  for (int e = rp[i]; e < e1; e++) {
    int s = cs[e];
    float wgt = dinv[s];
    float4 rrow = ld_bf4(H + (size_t)s * 256 + l * 4);
    acc.x += wgt * rrow.x; acc.y += wgt * rrow.y; acc.z += wgt * rrow.z; acc.w += wgt * rrow.w;
  }
  float4 b = *(const float4*)(bias + l * 4);
  float4 o;
  o.x = fmaxf(di * acc.x + b.x, 0.f);
  o.y = fmaxf(di * acc.y + b.y, 0.f);
  o.z = fmaxf(di * acc.z + b.z, 0.f);
  o.w = fmaxf(di * acc.w + b.w, 0.f);
  *(float4*)(out + (size_t)i * 256 + l * 4) = o;
}

template <int BIAS>
__global__ __launch_bounds__(256) void prop64(const unsigned short* __restrict__ H,
                                              const int* __restrict__ rp,
                                              const int* __restrict__ cs,
                                              const float* __restrict__ dinv,
                                              const float* __restrict__ bias,
                                              unsigned short* __restrict__ out, int n) {
  const int i = blockIdx.x * 16 + (threadIdx.x >> 4);
  const int l = threadIdx.x & 15;
  if (i >= n) return;
  const float di = dinv[i];
  float4 self = ld_bf4(H + (size_t)i * 64 + l * 4);
  float4 acc;
  acc.x = di * self.x; acc.y = di * self.y; acc.z = di * self.z; acc.w = di * self.w;
  const int e1 = rp[i + 1];
#pragma unroll 4
  for (int e = rp[i]; e < e1; e++) {
    int s = cs[e];
    float wgt = dinv[s];
    float4 rrow = ld_bf4(H + (size_t)s * 64 + l * 4);
    acc.x += wgt * rrow.x; acc.y += wgt * rrow.y; acc.z += wgt * rrow.z; acc.w += wgt * rrow.w;
  }
  float4 o;
  o.x = di * acc.x; o.y = di * acc.y; o.z = di * acc.z; o.w = di * acc.w;
  if (BIAS) {
    float4 b = *(const float4*)(bias + l * 4);
    o.x += b.x; o.y += b.y; o.z += b.z; o.w += b.w;
  }
  ushort4 ob;
  ob.x = f2bf(o.x); ob.y = f2bf(o.y); ob.z = f2bf(o.z); ob.w = f2bf(o.w);
  *(ushort4*)(out + (size_t)i * 64 + l * 4) = ob;
}

// ---------------- fused GEMM2 + final: out = (relu(q2@W21 + b21) + h1) @ Wfc + bfc ----------
__global__ __launch_bounds__(512) void gf(const unsigned short* __restrict__ A,   // q2b [M][64]
                                          const unsigned short* __restrict__ Bb,  // W21T [256][64]
                                          const float* __restrict__ h1,
                                          const float* __restrict__ b21,
                                          const float* __restrict__ Wfc,
                                          const float* __restrict__ bfc,
                                          float* __restrict__ out, int M) {
  __shared__ __attribute__((aligned(16))) float hsm[128 * 260];  // 133 KB; aliased by As/Bs in phase 1
  __shared__ __attribute__((aligned(16))) float wt[256 * 16];    // 16 KB Wfc
  unsigned short* As = (unsigned short*)hsm;       // 128x64 bf16 = 16 KB
  unsigned short* Bs = As + 128 * 64;              // 256x64 bf16 = 32 KB
  const int tid = threadIdx.x;
  const int w = tid >> 6, lane = tid & 63;
  const int row0 = blockIdx.x * 128;
  const int wm = w >> 2, wn = w & 3;               // 2M x 4N wave grid; wave = 64x64
  const int mlane = lane & 15, q = lane >> 4;

  for (int j = tid; j < 4096; j += 512) wt[j] = Wfc[j];
#pragma unroll
  for (int i = 0; i < 2; i++) {
    int gr = row0 + i * 64 + w * 8 + (lane >> 3);
    if (gr > M - 1) gr = M - 1;
    async16(A + (size_t)gr * 64 + (lane & 7) * 8, &As[(i * 64 + w * 8) * 64]);
  }
#pragma unroll
  for (int i = 0; i < 4; i++) {
    int n = i * 64 + w * 8 + (lane >> 3);
    async16(Bb + (size_t)n * 64 + (lane & 7) * 8, &Bs[(i * 64 + w * 8) * 64]);
  }
  __syncthreads();

  f32x4 acc[4][4];
#pragma unroll
  for (int mi = 0; mi < 4; mi++)
#pragma unroll
    for (int ni = 0; ni < 4; ni++) {
      f32x4 z = {0.f, 0.f, 0.f, 0.f};
      acc[mi][ni] = z;
    }
#pragma unroll
  for (int kk = 0; kk < 2; kk++) {
    bf16x8 af[4], bfr[4];
#pragma unroll
    for (int mi = 0; mi < 4; mi++)
      af[mi] = *(const bf16x8*)&As[(wm * 64 + mi * 16 + mlane) * 64 + kk * 32 + q * 8];
#pragma unroll
    for (int ni = 0; ni < 4; ni++)
      bfr[ni] = *(const bf16x8*)&Bs[(wn * 64 + ni * 16 + mlane) * 64 + kk * 32 + q * 8];
#pragma unroll
    for (int mi = 0; mi < 4; mi++)
#pragma unroll
      for (int ni = 0; ni < 4; ni++)
        acc[mi][ni] = __builtin_amdgcn_mfma_f32_16x16x32_bf16(af[mi], bfr[ni], acc[mi][ni], 0, 0, 0);
  }
  __syncthreads();  // all ds_reads of As/Bs done before hsm overwrites them

  // epilogue: h = relu(h3 + b21) + h1 -> hsm (f32)
#pragma unroll
  for (int ni = 0; ni < 4; ni++) {
    int c = wn * 64 + ni * 16 + mlane;
    float bb = b21[c];
#pragma unroll
    for (int mi = 0; mi < 4; mi++)
#pragma unroll
      for (int rg = 0; rg < 4; rg++) {
        int rl = wm * 64 + mi * 16 + q * 4 + rg;   // C/D: col=lane&15, row=(lane>>4)*4+reg
        int gr = row0 + rl;
        int grc = (gr < M) ? gr : (M - 1);
        float v = fmaxf(acc[mi][ni][rg] + bb, 0.f) + h1[(size_t)grc * 256 + c];
        hsm[rl * 260 + c] = v;
      }
  }
  __syncthreads();

  // GEMV: out[r][0..15] = hsm[r][:] @ wt + bfc ; 4 threads per row, 4 cols each
  const int r = tid >> 2, j0 = (tid & 3) * 4;
  const int gr = row0 + r;
  if (gr < M) {
    float4 s = *(const float4*)(bfc + j0);
    const float* hrow = &hsm[r * 260];
#pragma unroll 8
    for (int c4 = 0; c4 < 64; c4++) {
      float4 h4 = *(const float4*)(hrow + c4 * 4);
      const float* wp = &wt[(c4 * 4) * 16 + j0];
      float4 a0 = *(const float4*)(wp);
      float4 a1 = *(const float4*)(wp + 16);
      float4 a2 = *(const float4*)(wp + 32);
      float4 a3 = *(const float4*)(wp + 48);
      s.x += h4.x * a0.x + h4.y * a1.x + h4.z * a2.x + h4.w * a3.x;
      s.y += h4.x * a0.y + h4.y * a1.y + h4.z * a2.y + h4.w * a3.y;
      s.z += h4.x * a0.z + h4.y * a1.z + h4.z * a2.z + h4.w * a3.z;
      s.w += h4.x * a0.w + h4.y * a1.w + h4.z * a2.w + h4.w * a3.w;
    }
    *(float4*)(out + (size_t)gr * 16 + j0) = s;
  }
}

// ---------------- launch ----------------
extern "C" void kernel_launch(void* const* d_in, const int* in_sizes, int n_in,
                              void* d_out, int out_size, void* d_ws, size_t ws_size,
                              hipStream_t stream) {
  const float* X   = (const float*)d_in[0];
  const int*   ei1 = (const int*)d_in[1];
  const int*   ei2 = (const int*)d_in[2];
  const float* W10 = (const float*)d_in[3];
  const float* b10 = (const float*)d_in[4];
  const float* W20 = (const float*)d_in[5];
  const float* b20 = (const float*)d_in[6];
  const float* W21 = (const float*)d_in[7];
  const float* b21 = (const float*)d_in[8];
  const float* Wfc = (const float*)d_in[9];
  const float* bfc = (const float*)d_in[10];
  float* out = (float*)d_out;

  const int N = N_NODES;
  const int E1 = in_sizes[1] / 2, E2 = in_sizes[2] / 2;
  const int* src1 = ei1; const int* dst1 = ei1 + E1;
  const int* src2 = ei2; const int* dst2 = ei2 + E2;
  const int nch1 = (E1 + CHUNK - 1) / CHUNK, nch2 = (E2 + CHUNK - 1) / CHUNK;
  const int nchmax = (nch1 > nch2) ? nch1 : nch2;

  char* p = (char*)d_ws;
  auto alloc = [&](size_t b) { char* r = p; p += (b + 255) & ~(size_t)255; return (void*)r; };
  int* M1 = (int*)alloc((size_t)nch1 * NBKT * 4);
  int* M2 = (int*)alloc((size_t)nch2 * NBKT * 4);
  int* bases = (int*)alloc((size_t)2 * (NBKT + 1) * 4);
  unsigned* eb1 = (unsigned*)alloc((size_t)E1 * 4);
  unsigned* eb2 = (unsigned*)alloc((size_t)E2 * 4);
  int* rp1 = (int*)alloc((size_t)(N + 1) * 4);
  int* rp2 = (int*)alloc((size_t)(N + 1) * 4);
  float* dinv1 = (float*)alloc((size_t)N * 4);
  float* dinv2 = (float*)alloc((size_t)N * 4);
  int* csr1s = (int*)alloc((size_t)E1 * 4);
  int* csr2s = (int*)alloc((size_t)E2 * 4);
  unsigned short* WcatT = (unsigned short*)alloc(384 * 512 * 2);
  unsigned short* W21T  = (unsigned short*)alloc(256 * 64 * 2);
  unsigned short* Xh1b = (unsigned short*)alloc((size_t)N * 256 * 2);  // bf16 GEMM1 out (256 cols)
  unsigned short* Xh2b = (unsigned short*)alloc((size_t)N * 64 * 2);   // bf16 GEMM1 out (64 cols)
  unsigned short* h2b  = (unsigned short*)alloc((size_t)N * 64 * 2);
  unsigned short* q2b  = (unsigned short*)alloc((size_t)N * 64 * 2);
  float* h1 = (float*)alloc((size_t)N * 256 * 4);

  // CSR build (no global atomics)
  binA<<<dim3(nchmax, 2), 256, 0, stream>>>(dst1, dst2, M1, M2, E1, E2, nch1, nch2);
  bin_offsets<<<dim3(2), 512, 0, stream>>>(M1, M2, bases, nch1, nch2, E1, E2);
  binB<<<dim3(nchmax, 2), 256, 0, stream>>>(src1, dst1, M1, eb1, E1, nch1,
                                            src2, dst2, M2, eb2, E2, nch2);
  binC<<<dim3(NBKT, 2), 256, 0, stream>>>(eb1, eb2, bases, rp1, dinv1, csr1s,
                                          rp2, dinv2, csr2s, N);
  cvt_w<<<dim3((384 * 512 + 256 * 64 + 255) / 256), 256, 0, stream>>>(W10, W20, W21, WcatT, W21T);
  // Xh1b = bf16(x@W10), Xh2b = bf16(x@W20): BN=192, T14 prefetch + counted vmcnt
  g1w<<<dim3((N + 127) / 128, 2), 256, 0, stream>>>(X, WcatT, Xh1b, Xh2b, N);
  // h1 = relu(prop1(Xh1) + b10)  fp32
  prop256<<<dim3((N + 3) / 4), 256, 0, stream>>>(Xh1b, rp1, csr1s, dinv1, b10, h1, N);
  // h2 = prop2(Xh2) + b20  -> bf16
  prop64<1><<<dim3((N + 15) / 16), 256, 0, stream>>>(Xh2b, rp2, csr2s, dinv2, b20, h2b, N);
  // q2 = prop2(h2) -> bf16
  prop64<0><<<dim3((N + 15) / 16), 256, 0, stream>>>(h2b, rp2, csr2s, dinv2, nullptr, q2b, N);
  // out = (relu(q2@W21 + b21) + h1) @ Wfc + bfc   (h3 never hits HBM)
  gf<<<dim3((N + 127) / 128), 512, 0, stream>>>(q2b, W21T, h1, b21, Wfc, bfc, out, N);
}

// Round 4
// 392.374 us; speedup vs baseline: 1.0978x; 1.0978x over previous
//
#include <hip/hip_runtime.h>
#include <hip/hip_bf16.h>
#include <cstdint>
#include <cstddef>

#define N_NODES 50000
#define FDIM 512
#define NBKT 391        // ceil(50000/128) buckets of 128 dst nodes
#define CHUNK 8192      // edges per binning block
#define BCAP 4096       // max edges per bucket (Poisson(2046), sigma 45 -> cap is 45 sigma)

typedef __bf16 bf16_t;
typedef bf16_t bf16x8 __attribute__((ext_vector_type(8)));
typedef float f32x4 __attribute__((ext_vector_type(4)));

__device__ __forceinline__ unsigned short f2bf(float f) {
  union { float f; uint32_t u; } c; c.f = f;
  uint32_t u = c.u;
  uint32_t r = (u + 0x7fffu + ((u >> 16) & 1u)) >> 16;  // RNE
  return (unsigned short)r;
}
__device__ __forceinline__ float bf2f(unsigned short u) {
  union { uint32_t i; float f; } c; c.i = (uint32_t)u << 16; return c.f;
}
__device__ __forceinline__ float4 ld_bf4(const unsigned short* p) {
  ushort4 u = *(const ushort4*)p;
  float4 r; r.x = bf2f(u.x); r.y = bf2f(u.y); r.z = bf2f(u.z); r.w = bf2f(u.w);
  return r;
}
__device__ __forceinline__ void async16(const void* g, void* l) {
  __builtin_amdgcn_global_load_lds((const __attribute__((address_space(1))) void*)g,
                                   (__attribute__((address_space(3))) void*)l, 16, 0, 0);
}

// ---------------- CSR build: LDS-binned bucket sort, no global atomics ----------------
__global__ __launch_bounds__(256) void binA(const int* __restrict__ d1, const int* __restrict__ d2,
                                            int* __restrict__ M1, int* __restrict__ M2,
                                            int E1, int E2, int nch1, int nch2) {
  const int g = blockIdx.y;
  const int* dst = g ? d2 : d1;
  int* M = g ? M2 : M1;
  const int E = g ? E2 : E1;
  const int nch = g ? nch2 : nch1;
  const int chunk = blockIdx.x;
  if (chunk >= nch) return;
  __shared__ int cnt[NBKT];
  for (int j = threadIdx.x; j < NBKT; j += 256) cnt[j] = 0;
  __syncthreads();
  const int base = chunk * CHUNK;
#pragma unroll 4
  for (int i = 0; i < CHUNK / 256; i++) {
    int e = base + i * 256 + threadIdx.x;
    if (e < E) atomicAdd(&cnt[dst[e] >> 7], 1);
  }
  __syncthreads();
  for (int j = threadIdx.x; j < NBKT; j += 256) M[chunk * NBKT + j] = cnt[j];
}

__global__ __launch_bounds__(512) void bin_offsets(int* __restrict__ M1, int* __restrict__ M2,
                                                   int* __restrict__ bases,
                                                   int nch1, int nch2, int E1, int E2) {
  const int g = blockIdx.x;
  int* M = g ? M2 : M1;
  const int nch = g ? nch2 : nch1;
  int* base = bases + g * (NBKT + 1);
  const int E = g ? E2 : E1;
  const int t = threadIdx.x;
  __shared__ int tot[512];
  int running = 0;
  if (t < NBKT) {
#pragma unroll 4
    for (int b = 0; b < nch; b++) {
      int v = M[b * NBKT + t];
      M[b * NBKT + t] = running;
      running += v;
    }
  }
  tot[t] = (t < NBKT) ? running : 0;
  __syncthreads();
  for (int off = 1; off < 512; off <<= 1) {
    int u = (t >= off) ? tot[t - off] : 0;
    __syncthreads();
    tot[t] += u;
    __syncthreads();
  }
  int ex = (t == 0) ? 0 : tot[t - 1];
  if (t < NBKT) {
    base[t] = ex;
#pragma unroll 4
    for (int b = 0; b < nch; b++) M[b * NBKT + t] += ex;
  }
  if (t == NBKT) base[NBKT] = E;
}

__global__ __launch_bounds__(256) void binB(const int* __restrict__ s1, const int* __restrict__ d1,
                                            const int* __restrict__ M1, unsigned* __restrict__ eb1,
                                            int E1, int nch1,
                                            const int* __restrict__ s2, const int* __restrict__ d2,
                                            const int* __restrict__ M2, unsigned* __restrict__ eb2,
                                            int E2, int nch2) {
  const int g = blockIdx.y;
  const int* src = g ? s2 : s1;
  const int* dst = g ? d2 : d1;
  const int* M = g ? M2 : M1;
  unsigned* eb = g ? eb2 : eb1;
  const int E = g ? E2 : E1;
  const int nch = g ? nch2 : nch1;
  const int chunk = blockIdx.x;
  if (chunk >= nch) return;
  __shared__ int gbase[NBKT];
  __shared__ int cur[NBKT];
  for (int j = threadIdx.x; j < NBKT; j += 256) {
    gbase[j] = M[chunk * NBKT + j];
    cur[j] = 0;
  }
  __syncthreads();
  const int base = chunk * CHUNK;
#pragma unroll 4
  for (int i = 0; i < CHUNK / 256; i++) {
    int e = base + i * 256 + threadIdx.x;
    if (e < E) {
      int d = dst[e];
      int b = d >> 7;
      int pos = gbase[b] + atomicAdd(&cur[b], 1);
      eb[pos] = ((unsigned)d << 16) | (unsigned)src[e];
    }
  }
}

__global__ __launch_bounds__(256) void binC(const unsigned* __restrict__ eb1,
                                            const unsigned* __restrict__ eb2,
                                            const int* __restrict__ bases,
                                            int* __restrict__ rp1, float* __restrict__ dv1,
                                            int* __restrict__ cs1,
                                            int* __restrict__ rp2, float* __restrict__ dv2,
                                            int* __restrict__ cs2, int n) {
  const int g = blockIdx.y;
  const unsigned* eb = g ? eb2 : eb1;
  const int* base = bases + g * (NBKT + 1);
  int* rp = g ? rp2 : rp1;
  float* dv = g ? dv2 : dv1;
  int* cs = g ? cs2 : cs1;
  const int bkt = blockIdx.x;
  const int e0 = base[bkt], e1 = base[bkt + 1];
  const int cnt = e1 - e0;
  const int node0 = bkt << 7;
  const int t = threadIdx.x;
  __shared__ unsigned stage[BCAP];
  __shared__ int sorted[BCAP];
  __shared__ int dcnt[128], dcur[128], dscan[128];
  if (t < 128) dcnt[t] = 0;
  __syncthreads();
  for (int i = t; i < cnt; i += 256) {
    unsigned pe = eb[e0 + i];
    stage[i] = pe;
    atomicAdd(&dcnt[(pe >> 16) & 127], 1);
  }
  __syncthreads();
  if (t < 128) dscan[t] = dcnt[t];
  __syncthreads();
  for (int off = 1; off < 128; off <<= 1) {
    int u = (t < 128 && t >= off) ? dscan[t - off] : 0;
    __syncthreads();
    if (t < 128) dscan[t] += u;
    __syncthreads();
  }
  if (t < 128) {
    int ex = dscan[t] - dcnt[t];
    dcur[t] = ex;
    int node = node0 + t;
    if (node < n) {
      rp[node] = e0 + ex;
      dv[node] = rsqrtf((float)dcnt[t] + 1.0f);
    }
  }
  __syncthreads();
  for (int i = t; i < cnt; i += 256) {
    unsigned pe = stage[i];
    int d = (pe >> 16) & 127;
    int pos = atomicAdd(&dcur[d], 1);
    sorted[pos] = (int)(pe & 0xFFFFu);
  }
  __syncthreads();
  for (int i = t; i < cnt; i += 256) cs[e0 + i] = sorted[i];
  if (bkt == NBKT - 1 && t == 0) rp[n] = base[NBKT];
}

// ---------------- weight converts ----------------
// WcatT[384][512]: n<256 -> W10 col n; 256<=n<320 -> W20 col n-256; else 0 (pad)
// W21T[256][64]: W21 transposed
__global__ void cvt_w(const float* __restrict__ W10, const float* __restrict__ W20,
                      const float* __restrict__ W21, unsigned short* __restrict__ WcatT,
                      unsigned short* __restrict__ W21T) {
  int j = blockIdx.x * 256 + threadIdx.x;
  const int T1 = 384 * 512;
  if (j < T1) {
    int n = j >> 9, k = j & 511;
    float v = (n < 256) ? W10[k * 256 + n] : ((n < 320) ? W20[k * 64 + (n - 256)] : 0.f);
    WcatT[j] = f2bf(v);
  } else {
    int j2 = j - T1;
    if (j2 < 256 * 64) {
      int n = j2 >> 6, k = j2 & 63;
      W21T[j2] = f2bf(W21[k * 256 + n]);
    }
  }
}

// ---------------- fused cvt + GEMM1: [Xh1b|Xh2b] = bf16(X) @ WcatT^T ----------------
// BM=64, BN=320 (single y-tile: X f32 read EXACTLY ONCE), BK=64, grid 782, 4 waves.
// Each wave owns all 64 M-rows x 80 N-cols (mi=4, ni=5, 40 MFMA per k-step).
// LDS 48 KB (As 8K + Bs 40K) -> 3 blocks/CU (cross-block overlap hides barrier drain).
// T2 swizzle on 16B slots (slot ^= row&7): As reg-staged -> swizzled write + read;
// Bs via global_load_lds -> LINEAR dest + PRE-SWIZZLED global source (G21) + swizzled read.
// Kills the 16-way bank conflict of 128B-stride row-major frag reads (-> 2-way, free).
__global__ __launch_bounds__(256) void g2(const float* __restrict__ X,
                                          const unsigned short* __restrict__ B,
                                          unsigned short* __restrict__ o1,
                                          unsigned short* __restrict__ o2, int M) {
  __shared__ __attribute__((aligned(16))) unsigned short As[64 * 64];    // 8 KB
  __shared__ __attribute__((aligned(16))) unsigned short Bs[320 * 64];   // 40 KB
  const int tid = threadIdx.x;
  const int w = tid >> 6, lane = tid & 63;
  const int row0 = blockIdx.x * 64;
  const int mlane = lane & 15, q = lane >> 4;

  // A-stage coords: 4 float4/thread; j = i*256+tid -> row=j>>4 (0..63), col4=j&15
  const int ar = tid >> 4;   // +16 per i
  const int ac4 = tid & 15;

  f32x4 acc[4][5];
#pragma unroll
  for (int mi = 0; mi < 4; mi++)
#pragma unroll
    for (int ni = 0; ni < 5; ni++) {
      f32x4 z = {0.f, 0.f, 0.f, 0.f};
      acc[mi][ni] = z;
    }

  for (int k0 = 0; k0 < 512; k0 += 64) {
    __syncthreads();  // prior step's frag reads of As/Bs done
    // load A[k] f32 (issued first so latency overlaps B-issue + cvt)
    float4 areg[4];
#pragma unroll
    for (int i = 0; i < 4; i++) {
      int r = i * 16 + ar;
      int gr = row0 + r; if (gr > M - 1) gr = M - 1;  // clamp; stores masked in epilogue
      areg[i] = *(const float4*)(X + (size_t)gr * 512 + k0 + ac4 * 4);
    }
    // stage B[k]: 320 rows x 8 slots(16B) = 2560 chunks, 10/thread.
    // LDS dest linear (wave-uniform base + lane*16); source slot pre-swizzled.
#pragma unroll
    for (int i = 0; i < 10; i++) {
      int idx = i * 256 + tid;
      int rw = idx >> 3, c8 = idx & 7;
      int sslot = c8 ^ (rw & 7);
      async16(B + (size_t)rw * 512 + k0 + sslot * 8, &Bs[idx * 8]);
    }
    // cvt A -> LDS, swizzled: 16B slot (col4>>1) -> ^ (row&7)
#pragma unroll
    for (int i = 0; i < 4; i++) {
      int r = i * 16 + ar;
      ushort4 o;
      o.x = f2bf(areg[i].x); o.y = f2bf(areg[i].y);
      o.z = f2bf(areg[i].z); o.w = f2bf(areg[i].w);
      int slot = ((ac4 >> 1) ^ (r & 7));
      *(ushort4*)&As[r * 64 + slot * 8 + (ac4 & 1) * 4] = o;
    }
    __syncthreads();  // compiler drains vmcnt+lgkmcnt before barrier: As/Bs ready
#pragma unroll
    for (int kk = 0; kk < 2; kk++) {
      bf16x8 af[4], bfr[5];
#pragma unroll
      for (int mi = 0; mi < 4; mi++) {
        int r = mi * 16 + mlane;
        int slot = (kk * 4 + q) ^ (r & 7);
        af[mi] = *(const bf16x8*)&As[r * 64 + slot * 8];
      }
#pragma unroll
      for (int ni = 0; ni < 5; ni++) {
        int r = w * 80 + ni * 16 + mlane;
        int slot = (kk * 4 + q) ^ (r & 7);
        bfr[ni] = *(const bf16x8*)&Bs[r * 64 + slot * 8];
      }
#pragma unroll
      for (int mi = 0; mi < 4; mi++)
#pragma unroll
        for (int ni = 0; ni < 5; ni++)
          acc[mi][ni] = __builtin_amdgcn_mfma_f32_16x16x32_bf16(af[mi], bfr[ni], acc[mi][ni], 0, 0, 0);
    }
  }

#pragma unroll
  for (int mi = 0; mi < 4; mi++)
#pragma unroll
    for (int ni = 0; ni < 5; ni++) {
      int c = w * 80 + ni * 16 + mlane;
#pragma unroll
      for (int rg = 0; rg < 4; rg++) {
        int r = row0 + mi * 16 + q * 4 + rg;  // C/D: col=lane&15, row=(lane>>4)*4+reg
        if (r < M) {
          float v = acc[mi][ni][rg];
          if (c < 256) o1[(size_t)r * 256 + c] = f2bf(v);
          else o2[(size_t)r * 64 + (c - 256)] = f2bf(v);
        }
      }
    }
}

// ---------------- propagation (gather-CSR, bf16 rows, fp32 accum) ----------------
__global__ __launch_bounds__(256) void prop256(const unsigned short* __restrict__ H,
                                               const int* __restrict__ rp,
                                               const int* __restrict__ cs,
                                               const float* __restrict__ dinv,
                                               const float* __restrict__ bias,
                                               float* __restrict__ out, int n) {
  const int i = blockIdx.x * 4 + (threadIdx.x >> 6);
  const int l = threadIdx.x & 63;
  if (i >= n) return;
  const float di = dinv[i];
  float4 self = ld_bf4(H + (size_t)i * 256 + l * 4);
  float4 acc;
  acc.x = di * self.x; acc.y = di * self.y; acc.z = di * self.z; acc.w = di * self.w;
  const int e1 = rp[i + 1];
#pragma unroll 4
  for (int e = rp[i]; e < e1; e++) {
    int s = cs[e];
    float wgt = dinv[s];
    float4 rrow = ld_bf4(H + (size_t)s * 256 + l * 4);
    acc.x += wgt * rrow.x; acc.y += wgt * rrow.y; acc.z += wgt * rrow.z; acc.w += wgt * rrow.w;
  }
  float4 b = *(const float4*)(bias + l * 4);
  float4 o;
  o.x = fmaxf(di * acc.x + b.x, 0.f);
  o.y = fmaxf(di * acc.y + b.y, 0.f);
  o.z = fmaxf(di * acc.z + b.z, 0.f);
  o.w = fmaxf(di * acc.w + b.w, 0.f);
  *(float4*)(out + (size_t)i * 256 + l * 4) = o;
}

template <int BIAS>
__global__ __launch_bounds__(256) void prop64(const unsigned short* __restrict__ H,
                                              const int* __restrict__ rp,
                                              const int* __restrict__ cs,
                                              const float* __restrict__ dinv,
                                              const float* __restrict__ bias,
                                              unsigned short* __restrict__ out, int n) {
  const int i = blockIdx.x * 16 + (threadIdx.x >> 4);
  const int l = threadIdx.x & 15;
  if (i >= n) return;
  const float di = dinv[i];
  float4 self = ld_bf4(H + (size_t)i * 64 + l * 4);
  float4 acc;
  acc.x = di * self.x; acc.y = di * self.y; acc.z = di * self.z; acc.w = di * self.w;
  const int e1 = rp[i + 1];
#pragma unroll 4
  for (int e = rp[i]; e < e1; e++) {
    int s = cs[e];
    float wgt = dinv[s];
    float4 rrow = ld_bf4(H + (size_t)s * 64 + l * 4);
    acc.x += wgt * rrow.x; acc.y += wgt * rrow.y; acc.z += wgt * rrow.z; acc.w += wgt * rrow.w;
  }
  float4 o;
  o.x = di * acc.x; o.y = di * acc.y; o.z = di * acc.z; o.w = di * acc.w;
  if (BIAS) {
    float4 b = *(const float4*)(bias + l * 4);
    o.x += b.x; o.y += b.y; o.z += b.z; o.w += b.w;
  }
  ushort4 ob;
  ob.x = f2bf(o.x); ob.y = f2bf(o.y); ob.z = f2bf(o.z); ob.w = f2bf(o.w);
  *(ushort4*)(out + (size_t)i * 64 + l * 4) = ob;
}

// ---------------- fused GEMM2 + final: out = (relu(q2@W21 + b21) + h1) @ Wfc + bfc ----------
__global__ __launch_bounds__(512) void gf(const unsigned short* __restrict__ A,   // q2b [M][64]
                                          const unsigned short* __restrict__ Bb,  // W21T [256][64]
                                          const float* __restrict__ h1,
                                          const float* __restrict__ b21,
                                          const float* __restrict__ Wfc,
                                          const float* __restrict__ bfc,
                                          float* __restrict__ out, int M) {
  __shared__ __attribute__((aligned(16))) float hsm[128 * 260];  // 133 KB; aliased by As/Bs in phase 1
  __shared__ __attribute__((aligned(16))) float wt[256 * 16];    // 16 KB Wfc
  unsigned short* As = (unsigned short*)hsm;       // 128x64 bf16 = 16 KB
  unsigned short* Bs = As + 128 * 64;              // 256x64 bf16 = 32 KB
  const int tid = threadIdx.x;
  const int w = tid >> 6, lane = tid & 63;
  const int row0 = blockIdx.x * 128;
  const int wm = w >> 2, wn = w & 3;               // 2M x 4N wave grid; wave = 64x64
  const int mlane = lane & 15, q = lane >> 4;

  for (int j = tid; j < 4096; j += 512) wt[j] = Wfc[j];
#pragma unroll
  for (int i = 0; i < 2; i++) {
    int gr = row0 + i * 64 + w * 8 + (lane >> 3);
    if (gr > M - 1) gr = M - 1;
    async16(A + (size_t)gr * 64 + (lane & 7) * 8, &As[(i * 64 + w * 8) * 64]);
  }
#pragma unroll
  for (int i = 0; i < 4; i++) {
    int n = i * 64 + w * 8 + (lane >> 3);
    async16(Bb + (size_t)n * 64 + (lane & 7) * 8, &Bs[(i * 64 + w * 8) * 64]);
  }
  __syncthreads();

  f32x4 acc[4][4];
#pragma unroll
  for (int mi = 0; mi < 4; mi++)
#pragma unroll
    for (int ni = 0; ni < 4; ni++) {
      f32x4 z = {0.f, 0.f, 0.f, 0.f};
      acc[mi][ni] = z;
    }
#pragma unroll
  for (int kk = 0; kk < 2; kk++) {
    bf16x8 af[4], bfr[4];
#pragma unroll
    for (int mi = 0; mi < 4; mi++)
      af[mi] = *(const bf16x8*)&As[(wm * 64 + mi * 16 + mlane) * 64 + kk * 32 + q * 8];
#pragma unroll
    for (int ni = 0; ni < 4; ni++)
      bfr[ni] = *(const bf16x8*)&Bs[(wn * 64 + ni * 16 + mlane) * 64 + kk * 32 + q * 8];
#pragma unroll
    for (int mi = 0; mi < 4; mi++)
#pragma unroll
      for (int ni = 0; ni < 4; ni++)
        acc[mi][ni] = __builtin_amdgcn_mfma_f32_16x16x32_bf16(af[mi], bfr[ni], acc[mi][ni], 0, 0, 0);
  }
  __syncthreads();  // all ds_reads of As/Bs done before hsm overwrites them

  // epilogue: h = relu(h3 + b21) + h1 -> hsm (f32)
#pragma unroll
  for (int ni = 0; ni < 4; ni++) {
    int c = wn * 64 + ni * 16 + mlane;
    float bb = b21[c];
#pragma unroll
    for (int mi = 0; mi < 4; mi++)
#pragma unroll
      for (int rg = 0; rg < 4; rg++) {
        int rl = wm * 64 + mi * 16 + q * 4 + rg;   // C/D: col=lane&15, row=(lane>>4)*4+reg
        int gr = row0 + rl;
        int grc = (gr < M) ? gr : (M - 1);
        float v = fmaxf(acc[mi][ni][rg] + bb, 0.f) + h1[(size_t)grc * 256 + c];
        hsm[rl * 260 + c] = v;
      }
  }
  __syncthreads();

  // GEMV: out[r][0..15] = hsm[r][:] @ wt + bfc ; 4 threads per row, 4 cols each
  const int r = tid >> 2, j0 = (tid & 3) * 4;
  const int gr = row0 + r;
  if (gr < M) {
    float4 s = *(const float4*)(bfc + j0);
    const float* hrow = &hsm[r * 260];
#pragma unroll 8
    for (int c4 = 0; c4 < 64; c4++) {
      float4 h4 = *(const float4*)(hrow + c4 * 4);
      const float* wp = &wt[(c4 * 4) * 16 + j0];
      float4 a0 = *(const float4*)(wp);
      float4 a1 = *(const float4*)(wp + 16);
      float4 a2 = *(const float4*)(wp + 32);
      float4 a3 = *(const float4*)(wp + 48);
      s.x += h4.x * a0.x + h4.y * a1.x + h4.z * a2.x + h4.w * a3.x;
      s.y += h4.x * a0.y + h4.y * a1.y + h4.z * a2.y + h4.w * a3.y;
      s.z += h4.x * a0.z + h4.y * a1.z + h4.z * a2.z + h4.w * a3.z;
      s.w += h4.x * a0.w + h4.y * a1.w + h4.z * a2.w + h4.w * a3.w;
    }
    *(float4*)(out + (size_t)gr * 16 + j0) = s;
  }
}

// ---------------- launch ----------------
extern "C" void kernel_launch(void* const* d_in, const int* in_sizes, int n_in,
                              void* d_out, int out_size, void* d_ws, size_t ws_size,
                              hipStream_t stream) {
  const float* X   = (const float*)d_in[0];
  const int*   ei1 = (const int*)d_in[1];
  const int*   ei2 = (const int*)d_in[2];
  const float* W10 = (const float*)d_in[3];
  const float* b10 = (const float*)d_in[4];
  const float* W20 = (const float*)d_in[5];
  const float* b20 = (const float*)d_in[6];
  const float* W21 = (const float*)d_in[7];
  const float* b21 = (const float*)d_in[8];
  const float* Wfc = (const float*)d_in[9];
  const float* bfc = (const float*)d_in[10];
  float* out = (float*)d_out;

  const int N = N_NODES;
  const int E1 = in_sizes[1] / 2, E2 = in_sizes[2] / 2;
  const int* src1 = ei1; const int* dst1 = ei1 + E1;
  const int* src2 = ei2; const int* dst2 = ei2 + E2;
  const int nch1 = (E1 + CHUNK - 1) / CHUNK, nch2 = (E2 + CHUNK - 1) / CHUNK;
  const int nchmax = (nch1 > nch2) ? nch1 : nch2;

  char* p = (char*)d_ws;
  auto alloc = [&](size_t b) { char* r = p; p += (b + 255) & ~(size_t)255; return (void*)r; };
  int* M1 = (int*)alloc((size_t)nch1 * NBKT * 4);
  int* M2 = (int*)alloc((size_t)nch2 * NBKT * 4);
  int* bases = (int*)alloc((size_t)2 * (NBKT + 1) * 4);
  unsigned* eb1 = (unsigned*)alloc((size_t)E1 * 4);
  unsigned* eb2 = (unsigned*)alloc((size_t)E2 * 4);
  int* rp1 = (int*)alloc((size_t)(N + 1) * 4);
  int* rp2 = (int*)alloc((size_t)(N + 1) * 4);
  float* dinv1 = (float*)alloc((size_t)N * 4);
  float* dinv2 = (float*)alloc((size_t)N * 4);
  int* csr1s = (int*)alloc((size_t)E1 * 4);
  int* csr2s = (int*)alloc((size_t)E2 * 4);
  unsigned short* WcatT = (unsigned short*)alloc(384 * 512 * 2);
  unsigned short* W21T  = (unsigned short*)alloc(256 * 64 * 2);
  unsigned short* Xh1b = (unsigned short*)alloc((size_t)N * 256 * 2);  // bf16 GEMM1 out (256 cols)
  unsigned short* Xh2b = (unsigned short*)alloc((size_t)N * 64 * 2);   // bf16 GEMM1 out (64 cols)
  unsigned short* h2b  = (unsigned short*)alloc((size_t)N * 64 * 2);
  unsigned short* q2b  = (unsigned short*)alloc((size_t)N * 64 * 2);
  float* h1 = (float*)alloc((size_t)N * 256 * 4);

  // CSR build (no global atomics)
  binA<<<dim3(nchmax, 2), 256, 0, stream>>>(dst1, dst2, M1, M2, E1, E2, nch1, nch2);
  bin_offsets<<<dim3(2), 512, 0, stream>>>(M1, M2, bases, nch1, nch2, E1, E2);
  binB<<<dim3(nchmax, 2), 256, 0, stream>>>(src1, dst1, M1, eb1, E1, nch1,
                                            src2, dst2, M2, eb2, E2, nch2);
  binC<<<dim3(NBKT, 2), 256, 0, stream>>>(eb1, eb2, bases, rp1, dinv1, csr1s,
                                          rp2, dinv2, csr2s, N);
  cvt_w<<<dim3((384 * 512 + 256 * 64 + 255) / 256), 256, 0, stream>>>(W10, W20, W21, WcatT, W21T);
  // Xh1b = bf16(x@W10), Xh2b = bf16(x@W20): BM=64, BN=320 (X read once), swizzled LDS
  g2<<<dim3((N + 63) / 64), 256, 0, stream>>>(X, WcatT, Xh1b, Xh2b, N);
  // h1 = relu(prop1(Xh1) + b10)  fp32
  prop256<<<dim3((N + 3) / 4), 256, 0, stream>>>(Xh1b, rp1, csr1s, dinv1, b10, h1, N);
  // h2 = prop2(Xh2) + b20  -> bf16
  prop64<1><<<dim3((N + 15) / 16), 256, 0, stream>>>(Xh2b, rp2, csr2s, dinv2, b20, h2b, N);
  // q2 = prop2(h2) -> bf16
  prop64<0><<<dim3((N + 15) / 16), 256, 0, stream>>>(h2b, rp2, csr2s, dinv2, nullptr, q2b, N);
  // out = (relu(q2@W21 + b21) + h1) @ Wfc + bfc   (h3 never hits HBM)
  gf<<<dim3((N + 127) / 128), 512, 0, stream>>>(q2b, W21T, h1, b21, Wfc, bfc, out, N);
}